// Round 1
// baseline (61.751 us; speedup 1.0000x reference)
//
#include <hip/hip_runtime.h>

// Problem constants (from reference):
//   x: (N=128, S=16, D=512) f32, FM: (S+1, H=4) f32, Agg: (1, S, H) f32,
//   source_index: (2^S-1, S) i32  [UNUSED -- algebraically eliminated]
// Identity: out[n,h,d] = sum_j (FM[j+1,h]*Agg[j,h]) * x[n,j,d]
// (sort + gap encoding + cumsum-code table lookup telescopes to a plain
//  weighted sum over the source axis, permutation-invariant).
//
// This revision: 4 waves/block (was 1), S-reduction split across waves
// (4 j's each) + LDS combine. Same HBM traffic (4 MiB read, 1 MiB write);
// 4x the resident waves per CU and a 4-deep (was 16-deep) load chain per
// wave -> tests whether the kernel is still a latency-bound component of
// dur_us or whether we are at the harness floor.

#define CIE_S 16
#define CIE_H 4
#define CIE_N 128
#define CIE_D 512
#define CIE_D4 (CIE_D / 4)
#define CIE_WAVES 4
#define CIE_JPW (CIE_S / CIE_WAVES)   // 4 source rows per wave

__global__ __launch_bounds__(256)
void CIE_18236431138961_kernel(const float* __restrict__ x,
                               const float* __restrict__ FM,
                               const float* __restrict__ Agg,
                               float* __restrict__ out) {
    // lds[h][w-1][lane]: float4 partials from waves 1..3.
    // Lane-contiguous float4 -> 2-way bank aliasing only (free on CDNA4).
    __shared__ float4 lds[CIE_H][CIE_WAVES - 1][64];

    const int tid  = threadIdx.x;
    const int w    = tid >> 6;          // wave id 0..3 (uniform per wave)
    const int lane = tid & 63;
    const int e    = blockIdx.x * 64 + lane;   // 0 .. N*D4-1
    const int n    = e / CIE_D4;
    const int d4   = e % CIE_D4;

    // Per-wave weights: W[jj][h] = FM[j0+jj+1][h] * Agg[j0+jj][h]
    const int j0 = w * CIE_JPW;
    float W[CIE_JPW][CIE_H];
#pragma unroll
    for (int jj = 0; jj < CIE_JPW; ++jj) {
#pragma unroll
        for (int h = 0; h < CIE_H; ++h) {
            W[jj][h] = FM[(j0 + jj + 1) * CIE_H + h] * Agg[(j0 + jj) * CIE_H + h];
        }
    }

    const float4* __restrict__ x4 = (const float4*)x;

    float4 acc[CIE_H];
#pragma unroll
    for (int h = 0; h < CIE_H; ++h) acc[h] = make_float4(0.f, 0.f, 0.f, 0.f);

#pragma unroll
    for (int jj = 0; jj < CIE_JPW; ++jj) {
        const float4 v = x4[(n * CIE_S + j0 + jj) * CIE_D4 + d4];
#pragma unroll
        for (int h = 0; h < CIE_H; ++h) {
            acc[h].x += W[jj][h] * v.x;
            acc[h].y += W[jj][h] * v.y;
            acc[h].z += W[jj][h] * v.z;
            acc[h].w += W[jj][h] * v.w;
        }
    }

    if (w != 0) {
#pragma unroll
        for (int h = 0; h < CIE_H; ++h) lds[h][w - 1][lane] = acc[h];
    }
    __syncthreads();

    if (w == 0) {
#pragma unroll
        for (int h = 0; h < CIE_H; ++h) {
#pragma unroll
            for (int ww = 0; ww < CIE_WAVES - 1; ++ww) {
                const float4 p = lds[h][ww][lane];
                acc[h].x += p.x; acc[h].y += p.y;
                acc[h].z += p.z; acc[h].w += p.w;
            }
        }
        float4* __restrict__ out4 = (float4*)out;
#pragma unroll
        for (int h = 0; h < CIE_H; ++h) {
            out4[(n * CIE_H + h) * CIE_D4 + d4] = acc[h];
        }
    }
}

extern "C" void kernel_launch(void* const* d_in, const int* in_sizes, int n_in,
                              void* d_out, int out_size, void* d_ws, size_t ws_size,
                              hipStream_t stream) {
    const float* x   = (const float*)d_in[0];
    const float* FM  = (const float*)d_in[1];
    const float* Agg = (const float*)d_in[2];
    // d_in[3] = source_index: unused (algebraically eliminated).
    float* out = (float*)d_out;

    const int total = CIE_N * CIE_D4;        // 16384 output float4s
    const int grid  = total / 64;            // 256 blocks -> 1 per CU, 4 waves each

    CIE_18236431138961_kernel<<<grid, 256, 0, stream>>>(x, FM, Agg, out);
}